// Round 10
// baseline (59.224 us; speedup 1.0000x reference)
//
#include <hip/hip_runtime.h>

#define D 8192
#define T_STEPS 100
#define SPIKE_THR 0.5f

// ---- kernel 1 geometry: contiguous-slab reads ----
#define BLOCK1 512
#define WAVES1 (BLOCK1 / 64)                           // 8
#define NCHUNK 512
#define ROWS_PER_CHUNK (D / NCHUNK)                    // 16 rows = 512 KB slab
#define SEGS 4                                         // col segments/thread
#define NABS (NCHUNK * WAVES1)                         // 4096 |W| partials

// ---- kernel 2 geometry (proven 129-block structure) ----
#define BLOCK 256
#define RED_COLS 64
#define RED_SEGS (BLOCK / RED_COLS)                    // 4 waves
#define RED_BLOCKS (D / RED_COLS)                      // 128
#define CHUNKS_PER_SEG (NCHUNK / RED_SEGS)             // 128
#define STEPS_PER_SEG (T_STEPS / RED_SEGS)             // 25

// Kernel 1: each block streams a CONTIGUOUS 512 KB slab of W (16 full rows),
// accumulating partial drive for all 8192 columns (thread t owns cols
// s*2048 + 4t, s=0..3) + partial sum(|W|). grid = 512, block = 512.
// Sequential per-block streams maximize DRAM page hits.
__global__ void __launch_bounds__(BLOCK1)
k_partial(const float* __restrict__ x, const float* __restrict__ W,
          float* __restrict__ ws_drive, float* __restrict__ ws_abs) {
    const int chunk = blockIdx.x;
    const int row0  = chunk * ROWS_PER_CHUNK;
    const int t4    = threadIdx.x * 4;

    float4 a0 = {0.f,0.f,0.f,0.f}, a1 = {0.f,0.f,0.f,0.f};
    float4 a2 = {0.f,0.f,0.f,0.f}, a3 = {0.f,0.f,0.f,0.f};
    float asum = 0.f;

    #pragma unroll 2
    for (int r = 0; r < ROWS_PER_CHUNK; ++r) {
        const float xv = x[row0 + r];                  // uniform -> s_load
        const float* Wr = &W[(size_t)(row0 + r) * D + t4];
        const float4 w0 = *reinterpret_cast<const float4*>(Wr);
        const float4 w1 = *reinterpret_cast<const float4*>(Wr + 2048);
        const float4 w2 = *reinterpret_cast<const float4*>(Wr + 4096);
        const float4 w3 = *reinterpret_cast<const float4*>(Wr + 6144);
        a0.x = fmaf(xv, w0.x, a0.x); a0.y = fmaf(xv, w0.y, a0.y);
        a0.z = fmaf(xv, w0.z, a0.z); a0.w = fmaf(xv, w0.w, a0.w);
        a1.x = fmaf(xv, w1.x, a1.x); a1.y = fmaf(xv, w1.y, a1.y);
        a1.z = fmaf(xv, w1.z, a1.z); a1.w = fmaf(xv, w1.w, a1.w);
        a2.x = fmaf(xv, w2.x, a2.x); a2.y = fmaf(xv, w2.y, a2.y);
        a2.z = fmaf(xv, w2.z, a2.z); a2.w = fmaf(xv, w2.w, a2.w);
        a3.x = fmaf(xv, w3.x, a3.x); a3.y = fmaf(xv, w3.y, a3.y);
        a3.z = fmaf(xv, w3.z, a3.z); a3.w = fmaf(xv, w3.w, a3.w);
        asum += fabsf(w0.x) + fabsf(w0.y) + fabsf(w0.z) + fabsf(w0.w)
              + fabsf(w1.x) + fabsf(w1.y) + fabsf(w1.z) + fabsf(w1.w)
              + fabsf(w2.x) + fabsf(w2.y) + fabsf(w2.z) + fabsf(w2.w)
              + fabsf(w3.x) + fabsf(w3.y) + fabsf(w3.z) + fabsf(w3.w);
    }

    float* wd = &ws_drive[(size_t)chunk * D + t4];
    *reinterpret_cast<float4*>(wd)        = a0;
    *reinterpret_cast<float4*>(wd + 2048) = a1;
    *reinterpret_cast<float4*>(wd + 4096) = a2;
    *reinterpret_cast<float4*>(wd + 6144) = a3;

    // per-wave butterfly reduce of |W| partial (register-only, no barriers)
    #pragma unroll
    for (int off = 32; off > 0; off >>= 1)
        asum += __shfl_down(asum, off, 64);
    if ((threadIdx.x & 63) == 0)
        ws_abs[chunk * WAVES1 + (threadIdx.x >> 6)] = asum;
}

// Kernel 2 (fused): reduce ws_drive -> drive for 64 cols, then simulate.
// grid = RED_BLOCKS + 1 = 129, block = 256 = 4 waves.
// Wave `seg` sums a 128-chunk segment (256 B wave loads), LDS-combine, then
// warms up seg*25 steps in registers and stores its 25 timesteps.
// Block 128 reduces ws_abs -> activity scalar at out[2*T*D].
__global__ void __launch_bounds__(BLOCK)
k_fused(const float* __restrict__ ws_drive, const float* __restrict__ ws_abs,
        const float* __restrict__ pot0, float* __restrict__ out) {
    if (blockIdx.x == RED_BLOCKS) {
        __shared__ float red[BLOCK];
        float s = 0.f;
        for (int i = threadIdx.x; i < NABS; i += BLOCK) s += ws_abs[i];
        red[threadIdx.x] = s;
        __syncthreads();
        for (int st = BLOCK / 2; st > 0; st >>= 1) {
            if (threadIdx.x < st) red[threadIdx.x] += red[threadIdx.x + st];
            __syncthreads();
        }
        if (threadIdx.x == 0)
            out[(size_t)2 * T_STEPS * D] = red[0] / ((float)D * (float)D);
        return;
    }

    __shared__ float part[RED_SEGS][RED_COLS];
    const int col = threadIdx.x & (RED_COLS - 1);
    const int seg = threadIdx.x >> 6;                  // wave id, 0..3
    const int j   = blockIdx.x * RED_COLS + col;

    // each wave sums a 128-chunk segment for its column (256 B/wave loads)
    float s = 0.f;
    const int c0 = seg * CHUNKS_PER_SEG;
    #pragma unroll 8
    for (int cc = 0; cc < CHUNKS_PER_SEG; ++cc)
        s += ws_drive[(size_t)(c0 + cc) * D + j];
    part[seg][col] = s;
    __syncthreads();

    const float d = part[0][col] + part[1][col] + part[2][col] + part[3][col];
    float p = pot0[j];

    // warm up to this wave's time slice (register-only)
    const int t0 = seg * STEPS_PER_SEG;
    for (int t = 0; t < t0; ++t) {
        p += d;
        p = (p >= SPIKE_THR) ? 0.f : p;
    }

    float* __restrict__ spikes = out;
    float* __restrict__ pots   = out + (size_t)T_STEPS * D;

    #pragma unroll
    for (int s2 = 0; s2 < STEPS_PER_SEG; ++s2) {
        const int t = t0 + s2;
        p += d;
        const float sp = (p >= SPIKE_THR) ? 1.f : 0.f;
        p *= (1.f - sp);
        spikes[(size_t)t * D + j] = sp;
        pots[(size_t)t * D + j]   = p;
    }
}

extern "C" void kernel_launch(void* const* d_in, const int* in_sizes, int n_in,
                              void* d_out, int out_size, void* d_ws, size_t ws_size,
                              hipStream_t stream) {
    const float* x   = (const float*)d_in[0];
    const float* W   = (const float*)d_in[1];
    const float* mp0 = (const float*)d_in[2];
    float* out = (float*)d_out;

    float* ws_drive = (float*)d_ws;                       // NCHUNK*D floats = 16 MiB
    float* ws_abs   = ws_drive + (size_t)NCHUNK * D;      // NABS floats

    k_partial<<<NCHUNK, BLOCK1, 0, stream>>>(x, W, ws_drive, ws_abs);
    k_fused<<<RED_BLOCKS + 1, BLOCK, 0, stream>>>(ws_drive, ws_abs, mp0, out);
}

// Round 11
// 55.938 us; speedup vs baseline: 1.0588x; 1.0588x over previous
//
#include <hip/hip_runtime.h>

#define D 8192
#define T_STEPS 100
#define SPIKE_THR 0.5f
#define BLOCK 256
#define COLS_PER_THREAD 4
#define NCHUNK 128
#define ROWS_PER_CHUNK (D / NCHUNK)                    // 64
#define COLBLOCKS (D / (BLOCK * COLS_PER_THREAD))      // 8
#define RED_COLS 64                                    // cols per fused block
#define RED_SEGS (BLOCK / RED_COLS)                    // 4 waves
#define RED_BLOCKS (D / RED_COLS)                      // 128
#define CHUNKS_PER_SEG (NCHUNK / RED_SEGS)             // 32
#define STEPS_PER_SEG (T_STEPS / RED_SEGS)             // 25

// Kernel 1: partial column-dot-products over a 64-row chunk + partial sum(|W|).
// grid = (COLBLOCKS, NCHUNK) = (8, 128) = 1024 blocks = 4/CU = 16 waves/CU.
__global__ void __launch_bounds__(BLOCK)
k_partial(const float* __restrict__ x, const float* __restrict__ W,
          float* __restrict__ ws_drive, float* __restrict__ ws_abs) {
    __shared__ float xs[ROWS_PER_CHUNK];
    __shared__ float red[BLOCK];

    const int chunk = blockIdx.y;
    const int row0  = chunk * ROWS_PER_CHUNK;
    if (threadIdx.x < ROWS_PER_CHUNK)
        xs[threadIdx.x] = x[row0 + threadIdx.x];
    __syncthreads();

    const int j0 = (blockIdx.x * BLOCK + threadIdx.x) * COLS_PER_THREAD;

    float ax = 0.f, ay = 0.f, az = 0.f, aw = 0.f;
    float asum = 0.f;
    #pragma unroll 8
    for (int i = 0; i < ROWS_PER_CHUNK; ++i) {
        const float xv = xs[i];
        const float4 w = *reinterpret_cast<const float4*>(
            &W[(size_t)(row0 + i) * D + j0]);
        ax = fmaf(xv, w.x, ax);
        ay = fmaf(xv, w.y, ay);
        az = fmaf(xv, w.z, az);
        aw = fmaf(xv, w.w, aw);
        asum += fabsf(w.x) + fabsf(w.y) + fabsf(w.z) + fabsf(w.w);
    }

    float4 acc; acc.x = ax; acc.y = ay; acc.z = az; acc.w = aw;
    *reinterpret_cast<float4*>(&ws_drive[(size_t)chunk * D + j0]) = acc;

    red[threadIdx.x] = asum;
    __syncthreads();
    for (int s = BLOCK / 2; s > 0; s >>= 1) {
        if (threadIdx.x < s) red[threadIdx.x] += red[threadIdx.x + s];
        __syncthreads();
    }
    if (threadIdx.x == 0)
        ws_abs[blockIdx.y * gridDim.x + blockIdx.x] = red[0];
}

// Kernel 2 (fused): reduce ws_drive -> drive for 64 cols, then simulate.
// grid = RED_BLOCKS + 1 = 129, block = 256 = 4 waves.
// Wave `seg` sums a 32-chunk segment (256 B wave loads), LDS-combine, then
// warms up seg*25 steps in registers and stores its 25 timesteps.
// Block 128 reduces ws_abs -> activity scalar at out[2*T*D].
__global__ void __launch_bounds__(BLOCK)
k_fused(const float* __restrict__ ws_drive, const float* __restrict__ ws_abs,
        const float* __restrict__ pot0, float* __restrict__ out) {
    if (blockIdx.x == RED_BLOCKS) {
        __shared__ float red[BLOCK];
        const int n = NCHUNK * COLBLOCKS;  // 1024
        float s = 0.f;
        for (int i = threadIdx.x; i < n; i += BLOCK) s += ws_abs[i];
        red[threadIdx.x] = s;
        __syncthreads();
        for (int st = BLOCK / 2; st > 0; st >>= 1) {
            if (threadIdx.x < st) red[threadIdx.x] += red[threadIdx.x + st];
            __syncthreads();
        }
        if (threadIdx.x == 0)
            out[(size_t)2 * T_STEPS * D] = red[0] / ((float)D * (float)D);
        return;
    }

    __shared__ float part[RED_SEGS][RED_COLS];
    const int col = threadIdx.x & (RED_COLS - 1);
    const int seg = threadIdx.x >> 6;                  // wave id, 0..3
    const int j   = blockIdx.x * RED_COLS + col;

    // each wave sums a 32-chunk segment for its column (256 B/wave loads)
    float s = 0.f;
    const int c0 = seg * CHUNKS_PER_SEG;
    #pragma unroll 8
    for (int cc = 0; cc < CHUNKS_PER_SEG; ++cc)
        s += ws_drive[(size_t)(c0 + cc) * D + j];
    part[seg][col] = s;
    __syncthreads();

    const float d = part[0][col] + part[1][col] + part[2][col] + part[3][col];
    float p = pot0[j];

    // warm up to this wave's time slice (register-only)
    const int t0 = seg * STEPS_PER_SEG;
    for (int t = 0; t < t0; ++t) {
        p += d;
        p = (p >= SPIKE_THR) ? 0.f : p;
    }

    float* __restrict__ spikes = out;
    float* __restrict__ pots   = out + (size_t)T_STEPS * D;

    #pragma unroll
    for (int s2 = 0; s2 < STEPS_PER_SEG; ++s2) {
        const int t = t0 + s2;
        p += d;
        const float sp = (p >= SPIKE_THR) ? 1.f : 0.f;
        p *= (1.f - sp);
        spikes[(size_t)t * D + j] = sp;
        pots[(size_t)t * D + j]   = p;
    }
}

extern "C" void kernel_launch(void* const* d_in, const int* in_sizes, int n_in,
                              void* d_out, int out_size, void* d_ws, size_t ws_size,
                              hipStream_t stream) {
    const float* x   = (const float*)d_in[0];
    const float* W   = (const float*)d_in[1];
    const float* mp0 = (const float*)d_in[2];
    float* out = (float*)d_out;

    float* ws_drive = (float*)d_ws;                       // NCHUNK*D floats = 4 MiB
    float* ws_abs   = ws_drive + (size_t)NCHUNK * D;      // 1024 floats

    dim3 g1(COLBLOCKS, NCHUNK);
    k_partial<<<g1, BLOCK, 0, stream>>>(x, W, ws_drive, ws_abs);
    k_fused<<<RED_BLOCKS + 1, BLOCK, 0, stream>>>(ws_drive, ws_abs, mp0, out);
}